// Round 5
// baseline (1102.050 us; speedup 1.0000x reference)
//
#include <hip/hip_runtime.h>

// GCN: N=100000 nodes, E=1600000 edges, C_IN=128, C_HID=128, C_OUT=64.
// Pipeline per call:
//   detect int32/int64 -> degree count -> scan(+dinv) -> CSR fill (src only) ->
//   [gemm(row-scaled by dinv) -> aggregate] x3 -> z = h2@mlp_w1 -> per-edge MLP.
// R2: k_fill scatter wrote 155MB -> single-stream fill (dinv folded into GEMM).
// R4: k_gemm<64,64> pathology: full k-unroll hoisted all W loads -> VGPR=256,
//     occupancy 0.19%, 158us. Fix: unroll 2 + launch_bounds(256,4) + xs pad
//     (CIN+4: breaks 4-way bank conflict at CIN=64) + RSCALE templated.
//     k_fill: nontemporal scattered store (probe: WRITE_SIZE 106MB -> ~55MB?).

__device__ __forceinline__ int edge_at(const int* __restrict__ ei, long long idx, int is32) {
    return is32 ? ei[idx] : ei[2 * idx];
}

// Wave-reduced detect: OR odd words locally, <=1 atomic per wave.
__global__ __launch_bounds__(256) void k_detect(const int4* __restrict__ ei4, int nchunks,
                                                int* __restrict__ flag) {
    int acc = 0;
    for (int i = blockIdx.x * 256 + threadIdx.x; i < nchunks; i += gridDim.x * 256) {
        int4 v = ei4[i];
        acc |= v.y | v.w;
    }
    if (__any(acc != 0)) {
        if ((threadIdx.x & 63) == 0) atomicOr(flag, 1);
    }
}

__global__ __launch_bounds__(256) void k_count(const int* __restrict__ ei, int E, int* __restrict__ cnt,
                                               const int* __restrict__ flag) {
    int is32 = *flag;
    int e = blockIdx.x * 256 + threadIdx.x;
    if (e < E) {
        int d = edge_at(ei, (long long)E + e, is32);
        atomicAdd(&cnt[d], 1);
    }
}

// Exclusive scan of cnt within 1024-element chunks; block sums out.
__global__ __launch_bounds__(256) void k_scan_local(const int* __restrict__ cnt, int N,
                                                    int* __restrict__ offs, int* __restrict__ bsums) {
    __shared__ int wsum[4];
    int t = threadIdx.x;
    int lane = t & 63, wid = t >> 6;
    int gbase = blockIdx.x * 1024 + t * 4;
    int v0 = 0, v1 = 0, v2 = 0, v3 = 0;
    if (gbase + 0 < N) v0 = cnt[gbase + 0];
    if (gbase + 1 < N) v1 = cnt[gbase + 1];
    if (gbase + 2 < N) v2 = cnt[gbase + 2];
    if (gbase + 3 < N) v3 = cnt[gbase + 3];
    int tot = v0 + v1 + v2 + v3;
    int x = tot;
#pragma unroll
    for (int d = 1; d < 64; d <<= 1) {
        int y = __shfl_up(x, d);
        if (lane >= d) x += y;
    }
    if (lane == 63) wsum[wid] = x;
    __syncthreads();
    int wbase = 0;
#pragma unroll
    for (int w = 0; w < 4; w++)
        if (w < wid) wbase += wsum[w];
    int ex = wbase + x - tot;  // exclusive within chunk
    if (gbase + 0 < N) offs[gbase + 0] = ex;
    if (gbase + 1 < N) offs[gbase + 1] = ex + v0;
    if (gbase + 2 < N) offs[gbase + 2] = ex + v0 + v1;
    if (gbase + 3 < N) offs[gbase + 3] = ex + v0 + v1 + v2;
    if (t == 255) bsums[blockIdx.x] = wbase + x;
}

__global__ void k_scan_bsums(int* __restrict__ bsums, int nb) {
    int run = 0;
    for (int i = 0; i < nb; i++) {
        int v = bsums[i];
        bsums[i] = run;
        run += v;
    }
}

// offs += chunk base; also compute dinv here (fused, saves a launch).
__global__ __launch_bounds__(256) void k_scan_add(int* __restrict__ offs, const int* __restrict__ bsums,
                                                  const int* __restrict__ cnt, float* __restrict__ dinv, int N) {
    int i = blockIdx.x * 256 + threadIdx.x;
    if (i < N) {
        offs[i] += bsums[i >> 10];
        dinv[i] = rsqrtf((float)(cnt[i] + 1));  // +1: self-loop
    }
}

// Single scattered 4B stream; atomic cursor IS offs[] (ends up at end-offset).
// nt store: skip write-allocate on the random scatter (probe vs 106MB WRITE_SIZE).
__global__ __launch_bounds__(256) void k_fill(const int* __restrict__ ei, int E,
                                              int* __restrict__ offs, int* __restrict__ csr_src,
                                              const int* __restrict__ flag) {
    int is32 = *flag;
    int e = blockIdx.x * 256 + threadIdx.x;
    if (e < E) {
        int s = edge_at(ei, e, is32);
        int d = edge_at(ei, (long long)E + e, is32);
        int pos = atomicAdd(&offs[d], 1);
        __builtin_nontemporal_store(s, &csr_src[pos]);
    }
}

// ---------------- dense GEMM: Y[N,COUT] = rscale? ⊙ (X[N,CIN] @ W[CIN,COUT]) ----------------
// 64-row tile in LDS (padded leading dim), W from global (L1/L2-resident).
// unroll 2 + launch_bounds(,4): keep VGPR ~<100 so occupancy hides W-load latency.
template <int CIN, int COUT, bool RSCALE>
__global__ __launch_bounds__(256, 4) void k_gemm(const float* __restrict__ X, const float* __restrict__ W,
                                                 float* __restrict__ Y, int N,
                                                 const float* __restrict__ rscale) {
    constexpr int CT = COUT / 4;   // threads covering cols (float4 each)
    constexpr int RG = 256 / CT;   // row groups
    constexpr int RPT = 64 / RG;   // rows per thread
    constexpr int LDX = CIN + 4;   // pad: breaks same-bank row stride at CIN=64
    __shared__ float xs[64 * LDX];
    int t = threadIdx.x;
    int r0 = blockIdx.x * 64;
    int nrows = (N - r0 < 64) ? (N - r0) : 64;
    for (int c = t; c < 64 * (CIN / 4); c += 256) {
        int row = c / (CIN / 4);
        int col = (c % (CIN / 4)) * 4;
        float4 v = make_float4(0.f, 0.f, 0.f, 0.f);
        if (row < nrows) v = *(const float4*)&X[(size_t)(r0 + row) * CIN + col];
        *(float4*)&xs[row * LDX + col] = v;
    }
    __syncthreads();

    int ct = t % CT, rg = t / CT;
    float4 acc[RPT];
#pragma unroll
    for (int j = 0; j < RPT; j++) acc[j] = make_float4(0.f, 0.f, 0.f, 0.f);
    const float* wp = W + ct * 4;
#pragma unroll 2
    for (int k = 0; k < CIN; k += 4) {
        float4 w0 = *(const float4*)&wp[(size_t)(k + 0) * COUT];
        float4 w1 = *(const float4*)&wp[(size_t)(k + 1) * COUT];
        float4 w2 = *(const float4*)&wp[(size_t)(k + 2) * COUT];
        float4 w3 = *(const float4*)&wp[(size_t)(k + 3) * COUT];
#pragma unroll
        for (int j = 0; j < RPT; j++) {
            float4 a = *(const float4*)&xs[(rg * RPT + j) * LDX + k];
            acc[j].x += a.x * w0.x + a.y * w1.x + a.z * w2.x + a.w * w3.x;
            acc[j].y += a.x * w0.y + a.y * w1.y + a.z * w2.y + a.w * w3.y;
            acc[j].z += a.x * w0.z + a.y * w1.z + a.z * w2.z + a.w * w3.z;
            acc[j].w += a.x * w0.w + a.y * w1.w + a.z * w2.w + a.w * w3.w;
        }
    }
#pragma unroll
    for (int j = 0; j < RPT; j++) {
        int row = r0 + rg * RPT + j;
        if (row < N) {
            float4 o = acc[j];
            if constexpr (RSCALE) {
                float s = rscale[row];
                o.x *= s; o.y *= s; o.z *= s; o.w *= s;
            }
            *(float4*)&Y[(size_t)row * COUT + ct * 4] = o;
        }
    }
}

// ------- aggregation: H[i] = relu?(dinv_i * (sum_j T'[src_j] + T'[i]) + b) -------
// T' rows pre-scaled by dinv_src in the GEMM epilogue. One wave per node.
template <int C, bool RELU>
__global__ __launch_bounds__(256) void k_aggregate(const float* __restrict__ T, const int* __restrict__ offs,
                                                   const int* __restrict__ cnt, const int* __restrict__ csr_src,
                                                   const float* __restrict__ dinv,
                                                   const float* __restrict__ bias, float* __restrict__ H, int N) {
    int gw = (blockIdx.x * 256 + threadIdx.x) >> 6;
    int l = threadIdx.x & 63;
    if (gw >= N) return;
    float acc0 = 0.f, acc1 = 0.f;
    int num = cnt[gw];
    int start = offs[gw] - num;  // offs holds end offsets after k_fill
    for (int base = 0; base < num; base += 64) {
        int sv = 0;
        if (base + l < num) sv = csr_src[start + base + l];
        int m = num - base;
        if (m > 64) m = 64;
        for (int j = 0; j < m; j++) {
            int s = __shfl(sv, j);
            if constexpr (C == 128) {
                float2 tv = *(const float2*)&T[(size_t)s * C + l * 2];
                acc0 += tv.x;
                acc1 += tv.y;
            } else {
                acc0 += T[(size_t)s * C + l];
            }
        }
    }
    float di = dinv[gw];
    if constexpr (C == 128) {
        float2 ts = *(const float2*)&T[(size_t)gw * C + l * 2];
        float o0 = di * (acc0 + ts.x) + bias[l * 2 + 0];
        float o1 = di * (acc1 + ts.y) + bias[l * 2 + 1];
        if (RELU) {
            o0 = fmaxf(o0, 0.f);
            o1 = fmaxf(o1, 0.f);
        }
        *(float2*)&H[(size_t)gw * C + l * 2] = make_float2(o0, o1);
    } else {
        float o0 = di * (acc0 + T[(size_t)gw * C + l]) + bias[l];
        if (RELU) o0 = fmaxf(o0, 0.f);
        H[(size_t)gw * C + l] = o0;
    }
}

// ---------------- final per-edge MLP: y = relu(0.5*(z_s+z_d)+b1) @ w2 + b2 ----------------
__global__ __launch_bounds__(256) void k_edge_mlp(const int* __restrict__ ei, int E,
                                                  const float* __restrict__ Z, const float* __restrict__ b1,
                                                  const float* __restrict__ w2, const float* __restrict__ b2,
                                                  float* __restrict__ out, const int* __restrict__ flag) {
    int is32 = *flag;
    long long t = (long long)blockIdx.x * 256 + threadIdx.x;
    int e = (int)(t >> 4);
    int l = (int)(t & 15);
    if (e >= E) return;
    int s = edge_at(ei, e, is32);
    int d = edge_at(ei, (long long)E + e, is32);
    float4 zs = *(const float4*)&Z[(size_t)s * 64 + l * 4];
    float4 zd = *(const float4*)&Z[(size_t)d * 64 + l * 4];
    float4 bb = *(const float4*)&b1[l * 4];
    float4 u;
    u.x = fmaxf(0.f, 0.5f * (zs.x + zd.x) + bb.x);
    u.y = fmaxf(0.f, 0.5f * (zs.y + zd.y) + bb.y);
    u.z = fmaxf(0.f, 0.5f * (zs.z + zd.z) + bb.z);
    u.w = fmaxf(0.f, 0.5f * (zs.w + zd.w) + bb.w);
    float4 wa = *(const float4*)&w2[l * 8];      // rows l*4, l*4+1 (both cols)
    float4 wb = *(const float4*)&w2[l * 8 + 4];  // rows l*4+2, l*4+3
    float y0 = u.x * wa.x + u.y * wa.z + u.z * wb.x + u.w * wb.z;
    float y1 = u.x * wa.y + u.y * wa.w + u.z * wb.y + u.w * wb.w;
#pragma unroll
    for (int m = 1; m < 16; m <<= 1) {
        y0 += __shfl_xor(y0, m);
        y1 += __shfl_xor(y1, m);
    }
    if (l == 0) out[(size_t)e * 2 + 0] = y0 + b2[0];
    else if (l == 1) out[(size_t)e * 2 + 1] = y1 + b2[1];
}

extern "C" void kernel_launch(void* const* d_in, const int* in_sizes, int n_in,
                              void* d_out, int out_size, void* d_ws, size_t ws_size,
                              hipStream_t stream) {
    const float* x = (const float*)d_in[0];
    const int* ei = (const int*)d_in[1];
    const float* W0 = (const float*)d_in[2];
    const float* b0 = (const float*)d_in[3];
    const float* W1 = (const float*)d_in[4];
    const float* b1 = (const float*)d_in[5];
    const float* W2 = (const float*)d_in[6];
    const float* b2 = (const float*)d_in[7];
    const float* mw1 = (const float*)d_in[8];
    const float* mb1 = (const float*)d_in[9];
    const float* mw2 = (const float*)d_in[10];
    const float* mb2 = (const float*)d_in[11];
    float* out = (float*)d_out;

    int N = in_sizes[0] / 128;
    int E = in_sizes[1] / 2;

    char* p = (char*)d_ws;
    auto alloc = [&](size_t bytes) {
        char* q = p;
        p += (bytes + 255) & ~size_t(255);
        return q;
    };
    float* bufA = (float*)alloc((size_t)N * 128 * 4);
    float* bufB = (float*)alloc((size_t)N * 128 * 4);
    int* cnt = (int*)alloc((size_t)N * 4);
    int* offs = (int*)alloc((size_t)N * 4);
    float* dinv = (float*)alloc((size_t)N * 4);
    int* csr_src = (int*)alloc((size_t)E * 4);
    int* bsums = (int*)alloc(4096);
    int* flag = (int*)alloc(256);

    hipMemsetAsync(cnt, 0, (size_t)N * 4, stream);
    hipMemsetAsync(flag, 0, 4, stream);

    int gE = (E + 255) / 256;
    int gN = (N + 255) / 256;
    int nchunks = (2 * E) / 4;
    k_detect<<<1024, 256, 0, stream>>>((const int4*)ei, nchunks, flag);
    k_count<<<gE, 256, 0, stream>>>(ei, E, cnt, flag);
    int nb = (N + 1023) / 1024;
    k_scan_local<<<nb, 256, 0, stream>>>(cnt, N, offs, bsums);
    k_scan_bsums<<<1, 1, 0, stream>>>(bsums, nb);
    k_scan_add<<<gN, 256, 0, stream>>>(offs, bsums, cnt, dinv, N);
    k_fill<<<gE, 256, 0, stream>>>(ei, E, offs, csr_src, flag);

    int gG = (N + 63) / 64;
    int gA = (N + 3) / 4;  // N waves, 4 per block

    // layer 0: T' = dinv ⊙ (x@W0) ; h0 = relu(dinv ⊙ (agg(T')+T') + b0)
    k_gemm<128, 128, true><<<gG, 256, 0, stream>>>(x, W0, bufA, N, dinv);
    k_aggregate<128, true><<<gA, 256, 0, stream>>>(bufA, offs, cnt, csr_src, dinv, b0, bufB, N);
    // layer 1
    k_gemm<128, 128, true><<<gG, 256, 0, stream>>>(bufB, W1, bufA, N, dinv);
    k_aggregate<128, true><<<gA, 256, 0, stream>>>(bufA, offs, cnt, csr_src, dinv, b1, bufB, N);
    // layer 2 (no relu)
    k_gemm<128, 64, true><<<gG, 256, 0, stream>>>(bufB, W2, bufA, N, dinv);
    k_aggregate<64, false><<<gA, 256, 0, stream>>>(bufA, offs, cnt, csr_src, dinv, b2, bufB, N);
    // z = h2 @ mlp_w1 (linearity: ef@mlp_w1 = 0.5*(z_s+z_d)); unscaled
    k_gemm<64, 64, false><<<gG, 256, 0, stream>>>(bufB, mw1, bufA, N, nullptr);

    long long totalT = (long long)E * 16;
    int gM = (int)((totalT + 255) / 256);
    k_edge_mlp<<<gM, 256, 0, stream>>>(ei, E, bufA, mb1, mw2, mb2, out, flag);
}

// Round 7
// 988.783 us; speedup vs baseline: 1.1146x; 1.1146x over previous
//
#include <hip/hip_runtime.h>

// GCN: N=100000 nodes, E=1600000 edges, C_IN=128, C_HID=128, C_OUT=64.
// Pipeline per call:
//   detect int32/int64 -> count (+record per-edge rank) -> scan(+dinv) ->
//   CSR fill (atomic-free scatter) -> [gemm(dinv-scaled) -> aggregate] x3 ->
//   z = h2@mlp_w1 -> per-edge MLP.
// R2: k_fill wrote 155MB -> single scattered stream (dinv folded into GEMM).
// R4: k_gemm<64,64> VGPR=256/occ 0.19% -> unroll 2 + lb(256,4) + xs pad.
// R5: nt-store probe FAILED (WRITE_SIZE unchanged, +16us) -> reverted.
//     k_fill limiter = 1.6M device-scope atomicAdd RMW chains. Fix: k_count's
//     atomicAdd return IS the edge's rank -> store rank[e] (coalesced), k_fill
//     computes pos = offs[d] + rank[e] with no atomics.
// R6: broker timeout, no data — identical resubmit.

__device__ __forceinline__ int edge_at(const int* __restrict__ ei, long long idx, int is32) {
    return is32 ? ei[idx] : ei[2 * idx];
}

// Wave-reduced detect: OR odd words locally, <=1 atomic per wave.
__global__ __launch_bounds__(256) void k_detect(const int4* __restrict__ ei4, int nchunks,
                                                int* __restrict__ flag) {
    int acc = 0;
    for (int i = blockIdx.x * 256 + threadIdx.x; i < nchunks; i += gridDim.x * 256) {
        int4 v = ei4[i];
        acc |= v.y | v.w;
    }
    if (__any(acc != 0)) {
        if ((threadIdx.x & 63) == 0) atomicOr(flag, 1);
    }
}

// Count degrees AND record each edge's rank among same-dst edges (atomic order).
__global__ __launch_bounds__(256) void k_count(const int* __restrict__ ei, int E, int* __restrict__ cnt,
                                               int* __restrict__ rank, const int* __restrict__ flag) {
    int is32 = *flag;
    int e = blockIdx.x * 256 + threadIdx.x;
    if (e < E) {
        int d = edge_at(ei, (long long)E + e, is32);
        rank[e] = atomicAdd(&cnt[d], 1);
    }
}

// Exclusive scan of cnt within 1024-element chunks; block sums out.
__global__ __launch_bounds__(256) void k_scan_local(const int* __restrict__ cnt, int N,
                                                    int* __restrict__ offs, int* __restrict__ bsums) {
    __shared__ int wsum[4];
    int t = threadIdx.x;
    int lane = t & 63, wid = t >> 6;
    int gbase = blockIdx.x * 1024 + t * 4;
    int v0 = 0, v1 = 0, v2 = 0, v3 = 0;
    if (gbase + 0 < N) v0 = cnt[gbase + 0];
    if (gbase + 1 < N) v1 = cnt[gbase + 1];
    if (gbase + 2 < N) v2 = cnt[gbase + 2];
    if (gbase + 3 < N) v3 = cnt[gbase + 3];
    int tot = v0 + v1 + v2 + v3;
    int x = tot;
#pragma unroll
    for (int d = 1; d < 64; d <<= 1) {
        int y = __shfl_up(x, d);
        if (lane >= d) x += y;
    }
    if (lane == 63) wsum[wid] = x;
    __syncthreads();
    int wbase = 0;
#pragma unroll
    for (int w = 0; w < 4; w++)
        if (w < wid) wbase += wsum[w];
    int ex = wbase + x - tot;  // exclusive within chunk
    if (gbase + 0 < N) offs[gbase + 0] = ex;
    if (gbase + 1 < N) offs[gbase + 1] = ex + v0;
    if (gbase + 2 < N) offs[gbase + 2] = ex + v0 + v1;
    if (gbase + 3 < N) offs[gbase + 3] = ex + v0 + v1 + v2;
    if (t == 255) bsums[blockIdx.x] = wbase + x;
}

__global__ void k_scan_bsums(int* __restrict__ bsums, int nb) {
    int run = 0;
    for (int i = 0; i < nb; i++) {
        int v = bsums[i];
        bsums[i] = run;
        run += v;
    }
}

// offs += chunk base; also compute dinv here (fused, saves a launch).
__global__ __launch_bounds__(256) void k_scan_add(int* __restrict__ offs, const int* __restrict__ bsums,
                                                  const int* __restrict__ cnt, float* __restrict__ dinv, int N) {
    int i = blockIdx.x * 256 + threadIdx.x;
    if (i < N) {
        offs[i] += bsums[i >> 10];
        dinv[i] = rsqrtf((float)(cnt[i] + 1));  // +1: self-loop
    }
}

// Atomic-free scatter: pos = offs_excl[d] + rank[e]. All reads coalesced
// except the small offs gather; the store pipeline has no RMW dependence.
__global__ __launch_bounds__(256) void k_fill(const int* __restrict__ ei, int E,
                                              const int* __restrict__ offs, const int* __restrict__ rank,
                                              int* __restrict__ csr_src, const int* __restrict__ flag) {
    int is32 = *flag;
    int e = blockIdx.x * 256 + threadIdx.x;
    if (e < E) {
        int s = edge_at(ei, e, is32);
        int d = edge_at(ei, (long long)E + e, is32);
        int pos = offs[d] + rank[e];
        csr_src[pos] = s;
    }
}

// ---------------- dense GEMM: Y[N,COUT] = rscale? ⊙ (X[N,CIN] @ W[CIN,COUT]) ----------------
template <int CIN, int COUT, bool RSCALE>
__global__ __launch_bounds__(256, 4) void k_gemm(const float* __restrict__ X, const float* __restrict__ W,
                                                 float* __restrict__ Y, int N,
                                                 const float* __restrict__ rscale) {
    constexpr int CT = COUT / 4;   // threads covering cols (float4 each)
    constexpr int RG = 256 / CT;   // row groups
    constexpr int RPT = 64 / RG;   // rows per thread
    constexpr int LDX = CIN + 4;   // pad: breaks same-bank row stride at CIN=64
    __shared__ float xs[64 * LDX];
    int t = threadIdx.x;
    int r0 = blockIdx.x * 64;
    int nrows = (N - r0 < 64) ? (N - r0) : 64;
    for (int c = t; c < 64 * (CIN / 4); c += 256) {
        int row = c / (CIN / 4);
        int col = (c % (CIN / 4)) * 4;
        float4 v = make_float4(0.f, 0.f, 0.f, 0.f);
        if (row < nrows) v = *(const float4*)&X[(size_t)(r0 + row) * CIN + col];
        *(float4*)&xs[row * LDX + col] = v;
    }
    __syncthreads();

    int ct = t % CT, rg = t / CT;
    float4 acc[RPT];
#pragma unroll
    for (int j = 0; j < RPT; j++) acc[j] = make_float4(0.f, 0.f, 0.f, 0.f);
    const float* wp = W + ct * 4;
#pragma unroll 2
    for (int k = 0; k < CIN; k += 4) {
        float4 w0 = *(const float4*)&wp[(size_t)(k + 0) * COUT];
        float4 w1 = *(const float4*)&wp[(size_t)(k + 1) * COUT];
        float4 w2 = *(const float4*)&wp[(size_t)(k + 2) * COUT];
        float4 w3 = *(const float4*)&wp[(size_t)(k + 3) * COUT];
#pragma unroll
        for (int j = 0; j < RPT; j++) {
            float4 a = *(const float4*)&xs[(rg * RPT + j) * LDX + k];
            acc[j].x += a.x * w0.x + a.y * w1.x + a.z * w2.x + a.w * w3.x;
            acc[j].y += a.x * w0.y + a.y * w1.y + a.z * w2.y + a.w * w3.y;
            acc[j].z += a.x * w0.z + a.y * w1.z + a.z * w2.z + a.w * w3.z;
            acc[j].w += a.x * w0.w + a.y * w1.w + a.z * w2.w + a.w * w3.w;
        }
    }
#pragma unroll
    for (int j = 0; j < RPT; j++) {
        int row = r0 + rg * RPT + j;
        if (row < N) {
            float4 o = acc[j];
            if constexpr (RSCALE) {
                float s = rscale[row];
                o.x *= s; o.y *= s; o.z *= s; o.w *= s;
            }
            *(float4*)&Y[(size_t)row * COUT + ct * 4] = o;
        }
    }
}

// ------- aggregation: H[i] = relu?(dinv_i * (sum_j T'[src_j] + T'[i]) + b) -------
// T' rows pre-scaled by dinv_src in the GEMM epilogue. One wave per node.
template <int C, bool RELU>
__global__ __launch_bounds__(256) void k_aggregate(const float* __restrict__ T, const int* __restrict__ offs,
                                                   const int* __restrict__ cnt, const int* __restrict__ csr_src,
                                                   const float* __restrict__ dinv,
                                                   const float* __restrict__ bias, float* __restrict__ H, int N) {
    int gw = (blockIdx.x * 256 + threadIdx.x) >> 6;
    int l = threadIdx.x & 63;
    if (gw >= N) return;
    float acc0 = 0.f, acc1 = 0.f;
    int num = cnt[gw];
    int start = offs[gw];  // offs is exclusive (never mutated now)
    for (int base = 0; base < num; base += 64) {
        int sv = 0;
        if (base + l < num) sv = csr_src[start + base + l];
        int m = num - base;
        if (m > 64) m = 64;
        for (int j = 0; j < m; j++) {
            int s = __shfl(sv, j);
            if constexpr (C == 128) {
                float2 tv = *(const float2*)&T[(size_t)s * C + l * 2];
                acc0 += tv.x;
                acc1 += tv.y;
            } else {
                acc0 += T[(size_t)s * C + l];
            }
        }
    }
    float di = dinv[gw];
    if constexpr (C == 128) {
        float2 ts = *(const float2*)&T[(size_t)gw * C + l * 2];
        float o0 = di * (acc0 + ts.x) + bias[l * 2 + 0];
        float o1 = di * (acc1 + ts.y) + bias[l * 2 + 1];
        if (RELU) {
            o0 = fmaxf(o0, 0.f);
            o1 = fmaxf(o1, 0.f);
        }
        *(float2*)&H[(size_t)gw * C + l * 2] = make_float2(o0, o1);
    } else {
        float o0 = di * (acc0 + T[(size_t)gw * C + l]) + bias[l];
        if (RELU) o0 = fmaxf(o0, 0.f);
        H[(size_t)gw * C + l] = o0;
    }
}

// ---------------- final per-edge MLP: y = relu(0.5*(z_s+z_d)+b1) @ w2 + b2 ----------------
__global__ __launch_bounds__(256) void k_edge_mlp(const int* __restrict__ ei, int E,
                                                  const float* __restrict__ Z, const float* __restrict__ b1,
                                                  const float* __restrict__ w2, const float* __restrict__ b2,
                                                  float* __restrict__ out, const int* __restrict__ flag) {
    int is32 = *flag;
    long long t = (long long)blockIdx.x * 256 + threadIdx.x;
    int e = (int)(t >> 4);
    int l = (int)(t & 15);
    if (e >= E) return;
    int s = edge_at(ei, e, is32);
    int d = edge_at(ei, (long long)E + e, is32);
    float4 zs = *(const float4*)&Z[(size_t)s * 64 + l * 4];
    float4 zd = *(const float4*)&Z[(size_t)d * 64 + l * 4];
    float4 bb = *(const float4*)&b1[l * 4];
    float4 u;
    u.x = fmaxf(0.f, 0.5f * (zs.x + zd.x) + bb.x);
    u.y = fmaxf(0.f, 0.5f * (zs.y + zd.y) + bb.y);
    u.z = fmaxf(0.f, 0.5f * (zs.z + zd.z) + bb.z);
    u.w = fmaxf(0.f, 0.5f * (zs.w + zd.w) + bb.w);
    float4 wa = *(const float4*)&w2[l * 8];      // rows l*4, l*4+1 (both cols)
    float4 wb = *(const float4*)&w2[l * 8 + 4];  // rows l*4+2, l*4+3
    float y0 = u.x * wa.x + u.y * wa.z + u.z * wb.x + u.w * wb.z;
    float y1 = u.x * wa.y + u.y * wa.w + u.z * wb.y + u.w * wb.w;
#pragma unroll
    for (int m = 1; m < 16; m <<= 1) {
        y0 += __shfl_xor(y0, m);
        y1 += __shfl_xor(y1, m);
    }
    if (l == 0) out[(size_t)e * 2 + 0] = y0 + b2[0];
    else if (l == 1) out[(size_t)e * 2 + 1] = y1 + b2[1];
}

extern "C" void kernel_launch(void* const* d_in, const int* in_sizes, int n_in,
                              void* d_out, int out_size, void* d_ws, size_t ws_size,
                              hipStream_t stream) {
    const float* x = (const float*)d_in[0];
    const int* ei = (const int*)d_in[1];
    const float* W0 = (const float*)d_in[2];
    const float* b0 = (const float*)d_in[3];
    const float* W1 = (const float*)d_in[4];
    const float* b1 = (const float*)d_in[5];
    const float* W2 = (const float*)d_in[6];
    const float* b2 = (const float*)d_in[7];
    const float* mw1 = (const float*)d_in[8];
    const float* mb1 = (const float*)d_in[9];
    const float* mw2 = (const float*)d_in[10];
    const float* mb2 = (const float*)d_in[11];
    float* out = (float*)d_out;

    int N = in_sizes[0] / 128;
    int E = in_sizes[1] / 2;

    char* p = (char*)d_ws;
    auto alloc = [&](size_t bytes) {
        char* q = p;
        p += (bytes + 255) & ~size_t(255);
        return q;
    };
    float* bufA = (float*)alloc((size_t)N * 128 * 4);
    float* bufB = (float*)alloc((size_t)N * 128 * 4);
    int* cnt = (int*)alloc((size_t)N * 4);
    int* offs = (int*)alloc((size_t)N * 4);
    float* dinv = (float*)alloc((size_t)N * 4);
    int* csr_src = (int*)alloc((size_t)E * 4);
    int* rank = (int*)alloc((size_t)E * 4);
    int* bsums = (int*)alloc(4096);
    int* flag = (int*)alloc(256);

    hipMemsetAsync(cnt, 0, (size_t)N * 4, stream);
    hipMemsetAsync(flag, 0, 4, stream);

    int gE = (E + 255) / 256;
    int gN = (N + 255) / 256;
    int nchunks = (2 * E) / 4;
    k_detect<<<1024, 256, 0, stream>>>((const int4*)ei, nchunks, flag);
    k_count<<<gE, 256, 0, stream>>>(ei, E, cnt, rank, flag);
    int nb = (N + 1023) / 1024;
    k_scan_local<<<nb, 256, 0, stream>>>(cnt, N, offs, bsums);
    k_scan_bsums<<<1, 1, 0, stream>>>(bsums, nb);
    k_scan_add<<<gN, 256, 0, stream>>>(offs, bsums, cnt, dinv, N);
    k_fill<<<gE, 256, 0, stream>>>(ei, E, offs, rank, csr_src, flag);

    int gG = (N + 63) / 64;
    int gA = (N + 3) / 4;  // N waves, 4 per block

    // layer 0: T' = dinv ⊙ (x@W0) ; h0 = relu(dinv ⊙ (agg(T')+T') + b0)
    k_gemm<128, 128, true><<<gG, 256, 0, stream>>>(x, W0, bufA, N, dinv);
    k_aggregate<128, true><<<gA, 256, 0, stream>>>(bufA, offs, cnt, csr_src, dinv, b0, bufB, N);
    // layer 1
    k_gemm<128, 128, true><<<gG, 256, 0, stream>>>(bufB, W1, bufA, N, dinv);
    k_aggregate<128, true><<<gA, 256, 0, stream>>>(bufA, offs, cnt, csr_src, dinv, b1, bufB, N);
    // layer 2 (no relu)
    k_gemm<128, 64, true><<<gG, 256, 0, stream>>>(bufB, W2, bufA, N, dinv);
    k_aggregate<64, false><<<gA, 256, 0, stream>>>(bufA, offs, cnt, csr_src, dinv, b2, bufB, N);
    // z = h2 @ mlp_w1 (linearity: ef@mlp_w1 = 0.5*(z_s+z_d)); unscaled
    k_gemm<64, 64, false><<<gG, 256, 0, stream>>>(bufB, mw1, bufA, N, nullptr);

    long long totalT = (long long)E * 16;
    int gM = (int)((totalT + 255) / 256);
    k_edge_mlp<<<gM, 256, 0, stream>>>(ei, E, bufA, mb1, mw2, mb2, out, flag);
}

// Round 8
// 930.486 us; speedup vs baseline: 1.1844x; 1.0627x over previous
//
#include <hip/hip_runtime.h>

// GCN: N=100000 nodes, E=1600000 edges, C_IN=128, C_HID=128, C_OUT=64.
// Pipeline per call:
//   detect int32/int64 -> count (+record per-edge rank) -> scan(+dinv) ->
//   CSR fill (atomic-free scatter) -> [gemm(dinv-scaled) -> aggregate] x3 ->
//   z = h2@mlp_w1 -> per-edge MLP.
// R2: k_fill wrote 155MB -> single scattered stream (dinv folded into GEMM).
// R4: k_gemm<64,64> VGPR=256/occ 0.19% -> unroll 2 + lb(256,4) + xs pad.
// R5: nt-store FAILED -> reverted. R7: rank-from-count landed (k_fill out of
//     top-5; total 988us). New top: k_aggregate 130us x2, FETCH=403MB @3.56TB/s,
//     VALUBusy 19.7% -> latency-limited gather (1 row in flight per wave).
// R8: MLP-in-the-memory-sense fix: node per 32-lane group (C=128) / 16-lane
//     group (C=64) + 4-way unrolled gather -> ~8 rows in flight per wave.
//     Pre-registered: if dur unchanged & FETCH ~same -> L2-fill BW ceiling ->
//     next step is feature-chunked passes, not ILP.

__device__ __forceinline__ int edge_at(const int* __restrict__ ei, long long idx, int is32) {
    return is32 ? ei[idx] : ei[2 * idx];
}

// Wave-reduced detect: OR odd words locally, <=1 atomic per wave.
__global__ __launch_bounds__(256) void k_detect(const int4* __restrict__ ei4, int nchunks,
                                                int* __restrict__ flag) {
    int acc = 0;
    for (int i = blockIdx.x * 256 + threadIdx.x; i < nchunks; i += gridDim.x * 256) {
        int4 v = ei4[i];
        acc |= v.y | v.w;
    }
    if (__any(acc != 0)) {
        if ((threadIdx.x & 63) == 0) atomicOr(flag, 1);
    }
}

// Count degrees AND record each edge's rank among same-dst edges (atomic order).
__global__ __launch_bounds__(256) void k_count(const int* __restrict__ ei, int E, int* __restrict__ cnt,
                                               int* __restrict__ rank, const int* __restrict__ flag) {
    int is32 = *flag;
    int e = blockIdx.x * 256 + threadIdx.x;
    if (e < E) {
        int d = edge_at(ei, (long long)E + e, is32);
        rank[e] = atomicAdd(&cnt[d], 1);
    }
}

// Exclusive scan of cnt within 1024-element chunks; block sums out.
__global__ __launch_bounds__(256) void k_scan_local(const int* __restrict__ cnt, int N,
                                                    int* __restrict__ offs, int* __restrict__ bsums) {
    __shared__ int wsum[4];
    int t = threadIdx.x;
    int lane = t & 63, wid = t >> 6;
    int gbase = blockIdx.x * 1024 + t * 4;
    int v0 = 0, v1 = 0, v2 = 0, v3 = 0;
    if (gbase + 0 < N) v0 = cnt[gbase + 0];
    if (gbase + 1 < N) v1 = cnt[gbase + 1];
    if (gbase + 2 < N) v2 = cnt[gbase + 2];
    if (gbase + 3 < N) v3 = cnt[gbase + 3];
    int tot = v0 + v1 + v2 + v3;
    int x = tot;
#pragma unroll
    for (int d = 1; d < 64; d <<= 1) {
        int y = __shfl_up(x, d);
        if (lane >= d) x += y;
    }
    if (lane == 63) wsum[wid] = x;
    __syncthreads();
    int wbase = 0;
#pragma unroll
    for (int w = 0; w < 4; w++)
        if (w < wid) wbase += wsum[w];
    int ex = wbase + x - tot;  // exclusive within chunk
    if (gbase + 0 < N) offs[gbase + 0] = ex;
    if (gbase + 1 < N) offs[gbase + 1] = ex + v0;
    if (gbase + 2 < N) offs[gbase + 2] = ex + v0 + v1;
    if (gbase + 3 < N) offs[gbase + 3] = ex + v0 + v1 + v2;
    if (t == 255) bsums[blockIdx.x] = wbase + x;
}

__global__ void k_scan_bsums(int* __restrict__ bsums, int nb) {
    int run = 0;
    for (int i = 0; i < nb; i++) {
        int v = bsums[i];
        bsums[i] = run;
        run += v;
    }
}

// offs += chunk base; also compute dinv here (fused, saves a launch).
__global__ __launch_bounds__(256) void k_scan_add(int* __restrict__ offs, const int* __restrict__ bsums,
                                                  const int* __restrict__ cnt, float* __restrict__ dinv, int N) {
    int i = blockIdx.x * 256 + threadIdx.x;
    if (i < N) {
        offs[i] += bsums[i >> 10];
        dinv[i] = rsqrtf((float)(cnt[i] + 1));  // +1: self-loop
    }
}

// Atomic-free scatter: pos = offs_excl[d] + rank[e].
__global__ __launch_bounds__(256) void k_fill(const int* __restrict__ ei, int E,
                                              const int* __restrict__ offs, const int* __restrict__ rank,
                                              int* __restrict__ csr_src, const int* __restrict__ flag) {
    int is32 = *flag;
    int e = blockIdx.x * 256 + threadIdx.x;
    if (e < E) {
        int s = edge_at(ei, e, is32);
        int d = edge_at(ei, (long long)E + e, is32);
        int pos = offs[d] + rank[e];
        csr_src[pos] = s;
    }
}

// ---------------- dense GEMM: Y[N,COUT] = rscale? ⊙ (X[N,CIN] @ W[CIN,COUT]) ----------------
template <int CIN, int COUT, bool RSCALE>
__global__ __launch_bounds__(256, 4) void k_gemm(const float* __restrict__ X, const float* __restrict__ W,
                                                 float* __restrict__ Y, int N,
                                                 const float* __restrict__ rscale) {
    constexpr int CT = COUT / 4;   // threads covering cols (float4 each)
    constexpr int RG = 256 / CT;   // row groups
    constexpr int RPT = 64 / RG;   // rows per thread
    constexpr int LDX = CIN + 4;   // pad: breaks same-bank row stride at CIN=64
    __shared__ float xs[64 * LDX];
    int t = threadIdx.x;
    int r0 = blockIdx.x * 64;
    int nrows = (N - r0 < 64) ? (N - r0) : 64;
    for (int c = t; c < 64 * (CIN / 4); c += 256) {
        int row = c / (CIN / 4);
        int col = (c % (CIN / 4)) * 4;
        float4 v = make_float4(0.f, 0.f, 0.f, 0.f);
        if (row < nrows) v = *(const float4*)&X[(size_t)(r0 + row) * CIN + col];
        *(float4*)&xs[row * LDX + col] = v;
    }
    __syncthreads();

    int ct = t % CT, rg = t / CT;
    float4 acc[RPT];
#pragma unroll
    for (int j = 0; j < RPT; j++) acc[j] = make_float4(0.f, 0.f, 0.f, 0.f);
    const float* wp = W + ct * 4;
#pragma unroll 2
    for (int k = 0; k < CIN; k += 4) {
        float4 w0 = *(const float4*)&wp[(size_t)(k + 0) * COUT];
        float4 w1 = *(const float4*)&wp[(size_t)(k + 1) * COUT];
        float4 w2 = *(const float4*)&wp[(size_t)(k + 2) * COUT];
        float4 w3 = *(const float4*)&wp[(size_t)(k + 3) * COUT];
#pragma unroll
        for (int j = 0; j < RPT; j++) {
            float4 a = *(const float4*)&xs[(rg * RPT + j) * LDX + k];
            acc[j].x += a.x * w0.x + a.y * w1.x + a.z * w2.x + a.w * w3.x;
            acc[j].y += a.x * w0.y + a.y * w1.y + a.z * w2.y + a.w * w3.y;
            acc[j].z += a.x * w0.z + a.y * w1.z + a.z * w2.z + a.w * w3.z;
            acc[j].w += a.x * w0.w + a.y * w1.w + a.z * w2.w + a.w * w3.w;
        }
    }
#pragma unroll
    for (int j = 0; j < RPT; j++) {
        int row = r0 + rg * RPT + j;
        if (row < N) {
            float4 o = acc[j];
            if constexpr (RSCALE) {
                float s = rscale[row];
                o.x *= s; o.y *= s; o.z *= s; o.w *= s;
            }
            *(float4*)&Y[(size_t)row * COUT + ct * 4] = o;
        }
    }
}

// ------- aggregation: H[i] = relu?(dinv_i * (sum_j T'[src_j] + T'[i]) + b) -------
// One node per LANES-lane group (LANES*4 == C), float4 per lane.
// 4-way unrolled gather: up to 4 independent row loads in flight per group,
// (256/LANES) groups per block -> high memory-level parallelism.
template <int C, bool RELU>
__global__ __launch_bounds__(256) void k_aggregate(const float* __restrict__ T, const int* __restrict__ offs,
                                                   const int* __restrict__ cnt, const int* __restrict__ csr_src,
                                                   const float* __restrict__ dinv,
                                                   const float* __restrict__ bias, float* __restrict__ H, int N) {
    constexpr int LANES = C / 4;              // 32 for C=128, 16 for C=64
    constexpr int NPB = 256 / LANES;          // nodes per block
    int li = threadIdx.x & (LANES - 1);       // lane within group
    int g = threadIdx.x / LANES;              // group within block
    int gw = blockIdx.x * NPB + g;            // node id
    if (gw >= N) return;
    int gl0 = g * LANES;                      // first wave-lane of this group (within its wave: LANES<=64)
    // NOTE: __shfl indexes within the 64-lane wave; groups never straddle waves
    // since LANES is 16 or 32. Wave-local group base:
    int wl0 = (threadIdx.x & 63) - li;        // group base lane inside the wave
    (void)gl0;

    float4 acc = make_float4(0.f, 0.f, 0.f, 0.f);
    int num = cnt[gw];
    int start = offs[gw];  // exclusive offsets (never mutated)
    for (int base = 0; base < num; base += LANES) {
        int sv = 0;
        if (base + li < num) sv = csr_src[start + base + li];
        int m = num - base;
        if (m > LANES) m = LANES;
        int j = 0;
        for (; j + 4 <= m; j += 4) {
            int s0 = __shfl(sv, wl0 + j + 0);
            int s1 = __shfl(sv, wl0 + j + 1);
            int s2 = __shfl(sv, wl0 + j + 2);
            int s3 = __shfl(sv, wl0 + j + 3);
            float4 a0 = *(const float4*)&T[(size_t)s0 * C + li * 4];
            float4 a1 = *(const float4*)&T[(size_t)s1 * C + li * 4];
            float4 a2 = *(const float4*)&T[(size_t)s2 * C + li * 4];
            float4 a3 = *(const float4*)&T[(size_t)s3 * C + li * 4];
            acc.x += a0.x + a1.x + a2.x + a3.x;
            acc.y += a0.y + a1.y + a2.y + a3.y;
            acc.z += a0.z + a1.z + a2.z + a3.z;
            acc.w += a0.w + a1.w + a2.w + a3.w;
        }
        for (; j < m; j++) {
            int s = __shfl(sv, wl0 + j);
            float4 a = *(const float4*)&T[(size_t)s * C + li * 4];
            acc.x += a.x; acc.y += a.y; acc.z += a.z; acc.w += a.w;
        }
    }
    float di = dinv[gw];
    float4 ts = *(const float4*)&T[(size_t)gw * C + li * 4];
    float4 bb = *(const float4*)&bias[li * 4];
    float4 o;
    o.x = di * (acc.x + ts.x) + bb.x;
    o.y = di * (acc.y + ts.y) + bb.y;
    o.z = di * (acc.z + ts.z) + bb.z;
    o.w = di * (acc.w + ts.w) + bb.w;
    if (RELU) {
        o.x = fmaxf(o.x, 0.f); o.y = fmaxf(o.y, 0.f);
        o.z = fmaxf(o.z, 0.f); o.w = fmaxf(o.w, 0.f);
    }
    *(float4*)&H[(size_t)gw * C + li * 4] = o;
}

// ---------------- final per-edge MLP: y = relu(0.5*(z_s+z_d)+b1) @ w2 + b2 ----------------
__global__ __launch_bounds__(256) void k_edge_mlp(const int* __restrict__ ei, int E,
                                                  const float* __restrict__ Z, const float* __restrict__ b1,
                                                  const float* __restrict__ w2, const float* __restrict__ b2,
                                                  float* __restrict__ out, const int* __restrict__ flag) {
    int is32 = *flag;
    long long t = (long long)blockIdx.x * 256 + threadIdx.x;
    int e = (int)(t >> 4);
    int l = (int)(t & 15);
    if (e >= E) return;
    int s = edge_at(ei, e, is32);
    int d = edge_at(ei, (long long)E + e, is32);
    float4 zs = *(const float4*)&Z[(size_t)s * 64 + l * 4];
    float4 zd = *(const float4*)&Z[(size_t)d * 64 + l * 4];
    float4 bb = *(const float4*)&b1[l * 4];
    float4 u;
    u.x = fmaxf(0.f, 0.5f * (zs.x + zd.x) + bb.x);
    u.y = fmaxf(0.f, 0.5f * (zs.y + zd.y) + bb.y);
    u.z = fmaxf(0.f, 0.5f * (zs.z + zd.z) + bb.z);
    u.w = fmaxf(0.f, 0.5f * (zs.w + zd.w) + bb.w);
    float4 wa = *(const float4*)&w2[l * 8];      // rows l*4, l*4+1 (both cols)
    float4 wb = *(const float4*)&w2[l * 8 + 4];  // rows l*4+2, l*4+3
    float y0 = u.x * wa.x + u.y * wa.z + u.z * wb.x + u.w * wb.z;
    float y1 = u.x * wa.y + u.y * wa.w + u.z * wb.y + u.w * wb.w;
#pragma unroll
    for (int m = 1; m < 16; m <<= 1) {
        y0 += __shfl_xor(y0, m);
        y1 += __shfl_xor(y1, m);
    }
    if (l == 0) out[(size_t)e * 2 + 0] = y0 + b2[0];
    else if (l == 1) out[(size_t)e * 2 + 1] = y1 + b2[1];
}

extern "C" void kernel_launch(void* const* d_in, const int* in_sizes, int n_in,
                              void* d_out, int out_size, void* d_ws, size_t ws_size,
                              hipStream_t stream) {
    const float* x = (const float*)d_in[0];
    const int* ei = (const int*)d_in[1];
    const float* W0 = (const float*)d_in[2];
    const float* b0 = (const float*)d_in[3];
    const float* W1 = (const float*)d_in[4];
    const float* b1 = (const float*)d_in[5];
    const float* W2 = (const float*)d_in[6];
    const float* b2 = (const float*)d_in[7];
    const float* mw1 = (const float*)d_in[8];
    const float* mb1 = (const float*)d_in[9];
    const float* mw2 = (const float*)d_in[10];
    const float* mb2 = (const float*)d_in[11];
    float* out = (float*)d_out;

    int N = in_sizes[0] / 128;
    int E = in_sizes[1] / 2;

    char* p = (char*)d_ws;
    auto alloc = [&](size_t bytes) {
        char* q = p;
        p += (bytes + 255) & ~size_t(255);
        return q;
    };
    float* bufA = (float*)alloc((size_t)N * 128 * 4);
    float* bufB = (float*)alloc((size_t)N * 128 * 4);
    int* cnt = (int*)alloc((size_t)N * 4);
    int* offs = (int*)alloc((size_t)N * 4);
    float* dinv = (float*)alloc((size_t)N * 4);
    int* csr_src = (int*)alloc((size_t)E * 4);
    int* rank = (int*)alloc((size_t)E * 4);
    int* bsums = (int*)alloc(4096);
    int* flag = (int*)alloc(256);

    hipMemsetAsync(cnt, 0, (size_t)N * 4, stream);
    hipMemsetAsync(flag, 0, 4, stream);

    int gE = (E + 255) / 256;
    int gN = (N + 255) / 256;
    int nchunks = (2 * E) / 4;
    k_detect<<<1024, 256, 0, stream>>>((const int4*)ei, nchunks, flag);
    k_count<<<gE, 256, 0, stream>>>(ei, E, cnt, rank, flag);
    int nb = (N + 1023) / 1024;
    k_scan_local<<<nb, 256, 0, stream>>>(cnt, N, offs, bsums);
    k_scan_bsums<<<1, 1, 0, stream>>>(bsums, nb);
    k_scan_add<<<gN, 256, 0, stream>>>(offs, bsums, cnt, dinv, N);
    k_fill<<<gE, 256, 0, stream>>>(ei, E, offs, rank, csr_src, flag);

    int gG = (N + 63) / 64;
    int gA128 = (N + 7) / 8;    // 8 nodes/block (32-lane groups)
    int gA64 = (N + 15) / 16;   // 16 nodes/block (16-lane groups)

    // layer 0: T' = dinv ⊙ (x@W0) ; h0 = relu(dinv ⊙ (agg(T')+T') + b0)
    k_gemm<128, 128, true><<<gG, 256, 0, stream>>>(x, W0, bufA, N, dinv);
    k_aggregate<128, true><<<gA128, 256, 0, stream>>>(bufA, offs, cnt, csr_src, dinv, b0, bufB, N);
    // layer 1
    k_gemm<128, 128, true><<<gG, 256, 0, stream>>>(bufB, W1, bufA, N, dinv);
    k_aggregate<128, true><<<gA128, 256, 0, stream>>>(bufA, offs, cnt, csr_src, dinv, b1, bufB, N);
    // layer 2 (no relu)
    k_gemm<128, 64, true><<<gG, 256, 0, stream>>>(bufB, W2, bufA, N, dinv);
    k_aggregate<64, false><<<gA64, 256, 0, stream>>>(bufA, offs, cnt, csr_src, dinv, b2, bufB, N);
    // z = h2 @ mlp_w1 (linearity: ef@mlp_w1 = 0.5*(z_s+z_d)); unscaled
    k_gemm<64, 64, false><<<gG, 256, 0, stream>>>(bufB, mw1, bufA, N, nullptr);

    long long totalT = (long long)E * 16;
    int gM = (int)((totalT + 255) / 256);
    k_edge_mlp<<<gM, 256, 0, stream>>>(ei, E, bufA, mb1, mw2, mb2, out, flag);
}

// Round 9
// 688.201 us; speedup vs baseline: 1.6013x; 1.3521x over previous
//
#include <hip/hip_runtime.h>

// GCN: N=100000 nodes, E=1600000 edges, C_IN=128, C_HID=128, C_OUT=64.
// Pipeline per call:
//   detect int32/int64 -> count (+rank) -> scan(+dinv) -> CSR fill ->
//   [gemm(dinv-scaled, bf16 out) -> aggregate(bf16 in, fp32 out)] x3 ->
//   z = h2@mlp_w1 (bf16) -> per-edge MLP.
// R2: k_fill 155MB scatter -> single stream. R4: gemm<64,64> unroll/VGPR fix.
// R5: nt-store FAILED. R7: rank-from-count (k_fill atomic-free). R8: 4x MLP in
//     aggregate gave only -4% (FETCH unchanged 400MB, VALUBusy 19.7->11%):
//     random 512B-row gather is at its BW plateau (~3.7TB/s miss traffic).
// R9: halve gather bytes: all gathered tables (T'0,T'1,T'2,Z) stored bf16 at
//     GEMM epilogue (RNE); gather ushort4/lane, accumulate fp32; aggregate
//     outputs stay fp32. Predicted absmax ~1.2e-3 (<2.5e-3 threshold).

__device__ __forceinline__ int edge_at(const int* __restrict__ ei, long long idx, int is32) {
    return is32 ? ei[idx] : ei[2 * idx];
}

// float -> bf16 (round-to-nearest-even), bit-level (no header dependency)
__device__ __forceinline__ unsigned short f2bf(float f) {
    unsigned int u = __float_as_uint(f);
    u += 0x7FFFu + ((u >> 16) & 1u);
    return (unsigned short)(u >> 16);
}
__device__ __forceinline__ float bf2f(unsigned short h) {
    return __uint_as_float(((unsigned int)h) << 16);
}

// Wave-reduced detect: OR odd words locally, <=1 atomic per wave.
__global__ __launch_bounds__(256) void k_detect(const int4* __restrict__ ei4, int nchunks,
                                                int* __restrict__ flag) {
    int acc = 0;
    for (int i = blockIdx.x * 256 + threadIdx.x; i < nchunks; i += gridDim.x * 256) {
        int4 v = ei4[i];
        acc |= v.y | v.w;
    }
    if (__any(acc != 0)) {
        if ((threadIdx.x & 63) == 0) atomicOr(flag, 1);
    }
}

// Count degrees AND record each edge's rank among same-dst edges (atomic order).
__global__ __launch_bounds__(256) void k_count(const int* __restrict__ ei, int E, int* __restrict__ cnt,
                                               int* __restrict__ rank, const int* __restrict__ flag) {
    int is32 = *flag;
    int e = blockIdx.x * 256 + threadIdx.x;
    if (e < E) {
        int d = edge_at(ei, (long long)E + e, is32);
        rank[e] = atomicAdd(&cnt[d], 1);
    }
}

// Exclusive scan of cnt within 1024-element chunks; block sums out.
__global__ __launch_bounds__(256) void k_scan_local(const int* __restrict__ cnt, int N,
                                                    int* __restrict__ offs, int* __restrict__ bsums) {
    __shared__ int wsum[4];
    int t = threadIdx.x;
    int lane = t & 63, wid = t >> 6;
    int gbase = blockIdx.x * 1024 + t * 4;
    int v0 = 0, v1 = 0, v2 = 0, v3 = 0;
    if (gbase + 0 < N) v0 = cnt[gbase + 0];
    if (gbase + 1 < N) v1 = cnt[gbase + 1];
    if (gbase + 2 < N) v2 = cnt[gbase + 2];
    if (gbase + 3 < N) v3 = cnt[gbase + 3];
    int tot = v0 + v1 + v2 + v3;
    int x = tot;
#pragma unroll
    for (int d = 1; d < 64; d <<= 1) {
        int y = __shfl_up(x, d);
        if (lane >= d) x += y;
    }
    if (lane == 63) wsum[wid] = x;
    __syncthreads();
    int wbase = 0;
#pragma unroll
    for (int w = 0; w < 4; w++)
        if (w < wid) wbase += wsum[w];
    int ex = wbase + x - tot;  // exclusive within chunk
    if (gbase + 0 < N) offs[gbase + 0] = ex;
    if (gbase + 1 < N) offs[gbase + 1] = ex + v0;
    if (gbase + 2 < N) offs[gbase + 2] = ex + v0 + v1;
    if (gbase + 3 < N) offs[gbase + 3] = ex + v0 + v1 + v2;
    if (t == 255) bsums[blockIdx.x] = wbase + x;
}

__global__ void k_scan_bsums(int* __restrict__ bsums, int nb) {
    int run = 0;
    for (int i = 0; i < nb; i++) {
        int v = bsums[i];
        bsums[i] = run;
        run += v;
    }
}

// offs += chunk base; also compute dinv here (fused, saves a launch).
__global__ __launch_bounds__(256) void k_scan_add(int* __restrict__ offs, const int* __restrict__ bsums,
                                                  const int* __restrict__ cnt, float* __restrict__ dinv, int N) {
    int i = blockIdx.x * 256 + threadIdx.x;
    if (i < N) {
        offs[i] += bsums[i >> 10];
        dinv[i] = rsqrtf((float)(cnt[i] + 1));  // +1: self-loop
    }
}

// Atomic-free scatter: pos = offs_excl[d] + rank[e].
__global__ __launch_bounds__(256) void k_fill(const int* __restrict__ ei, int E,
                                              const int* __restrict__ offs, const int* __restrict__ rank,
                                              int* __restrict__ csr_src, const int* __restrict__ flag) {
    int is32 = *flag;
    int e = blockIdx.x * 256 + threadIdx.x;
    if (e < E) {
        int s = edge_at(ei, e, is32);
        int d = edge_at(ei, (long long)E + e, is32);
        int pos = offs[d] + rank[e];
        csr_src[pos] = s;
    }
}

// -------- dense GEMM: Ybf16[N,COUT] = f2bf( rscale? ⊙ (X[N,CIN] @ W[CIN,COUT]) ) --------
template <int CIN, int COUT, bool RSCALE>
__global__ __launch_bounds__(256, 4) void k_gemm(const float* __restrict__ X, const float* __restrict__ W,
                                                 unsigned short* __restrict__ Y, int N,
                                                 const float* __restrict__ rscale) {
    constexpr int CT = COUT / 4;   // threads covering cols (float4 each)
    constexpr int RG = 256 / CT;   // row groups
    constexpr int RPT = 64 / RG;   // rows per thread
    constexpr int LDX = CIN + 4;   // pad: breaks same-bank row stride at CIN=64
    __shared__ float xs[64 * LDX];
    int t = threadIdx.x;
    int r0 = blockIdx.x * 64;
    int nrows = (N - r0 < 64) ? (N - r0) : 64;
    for (int c = t; c < 64 * (CIN / 4); c += 256) {
        int row = c / (CIN / 4);
        int col = (c % (CIN / 4)) * 4;
        float4 v = make_float4(0.f, 0.f, 0.f, 0.f);
        if (row < nrows) v = *(const float4*)&X[(size_t)(r0 + row) * CIN + col];
        *(float4*)&xs[row * LDX + col] = v;
    }
    __syncthreads();

    int ct = t % CT, rg = t / CT;
    float4 acc[RPT];
#pragma unroll
    for (int j = 0; j < RPT; j++) acc[j] = make_float4(0.f, 0.f, 0.f, 0.f);
    const float* wp = W + ct * 4;
#pragma unroll 2
    for (int k = 0; k < CIN; k += 4) {
        float4 w0 = *(const float4*)&wp[(size_t)(k + 0) * COUT];
        float4 w1 = *(const float4*)&wp[(size_t)(k + 1) * COUT];
        float4 w2 = *(const float4*)&wp[(size_t)(k + 2) * COUT];
        float4 w3 = *(const float4*)&wp[(size_t)(k + 3) * COUT];
#pragma unroll
        for (int j = 0; j < RPT; j++) {
            float4 a = *(const float4*)&xs[(rg * RPT + j) * LDX + k];
            acc[j].x += a.x * w0.x + a.y * w1.x + a.z * w2.x + a.w * w3.x;
            acc[j].y += a.x * w0.y + a.y * w1.y + a.z * w2.y + a.w * w3.y;
            acc[j].z += a.x * w0.z + a.y * w1.z + a.z * w2.z + a.w * w3.z;
            acc[j].w += a.x * w0.w + a.y * w1.w + a.z * w2.w + a.w * w3.w;
        }
    }
#pragma unroll
    for (int j = 0; j < RPT; j++) {
        int row = r0 + rg * RPT + j;
        if (row < N) {
            float4 a = acc[j];
            if constexpr (RSCALE) {
                float s = rscale[row];
                a.x *= s; a.y *= s; a.z *= s; a.w *= s;
            }
            ushort4 o;
            o.x = f2bf(a.x); o.y = f2bf(a.y); o.z = f2bf(a.z); o.w = f2bf(a.w);
            *(ushort4*)&Y[(size_t)row * COUT + ct * 4] = o;
        }
    }
}

// ------- aggregation: H[i] = relu?(dinv_i * (sum_j T'[src_j] + T'[i]) + b) -------
// T' is bf16 [N,C]. One node per LANES-lane group (LANES*4 == C), ushort4/lane.
// 4-way unrolled gather keeps multiple 256B rows in flight; fp32 accumulate.
template <int C, bool RELU>
__global__ __launch_bounds__(256) void k_aggregate(const unsigned short* __restrict__ T,
                                                   const int* __restrict__ offs,
                                                   const int* __restrict__ cnt, const int* __restrict__ csr_src,
                                                   const float* __restrict__ dinv,
                                                   const float* __restrict__ bias, float* __restrict__ H, int N) {
    constexpr int LANES = C / 4;              // 32 for C=128, 16 for C=64
    constexpr int NPB = 256 / LANES;          // nodes per block
    int li = threadIdx.x & (LANES - 1);       // lane within group
    int g = threadIdx.x / LANES;              // group within block
    int gw = blockIdx.x * NPB + g;            // node id
    if (gw >= N) return;
    int wl0 = (threadIdx.x & 63) - li;        // group base lane inside the wave

    float4 acc = make_float4(0.f, 0.f, 0.f, 0.f);
    int num = cnt[gw];
    int start = offs[gw];  // exclusive offsets (never mutated)
    for (int base = 0; base < num; base += LANES) {
        int sv = 0;
        if (base + li < num) sv = csr_src[start + base + li];
        int m = num - base;
        if (m > LANES) m = LANES;
        int j = 0;
        for (; j + 4 <= m; j += 4) {
            int s0 = __shfl(sv, wl0 + j + 0);
            int s1 = __shfl(sv, wl0 + j + 1);
            int s2 = __shfl(sv, wl0 + j + 2);
            int s3 = __shfl(sv, wl0 + j + 3);
            ushort4 a0 = *(const ushort4*)&T[(size_t)s0 * C + li * 4];
            ushort4 a1 = *(const ushort4*)&T[(size_t)s1 * C + li * 4];
            ushort4 a2 = *(const ushort4*)&T[(size_t)s2 * C + li * 4];
            ushort4 a3 = *(const ushort4*)&T[(size_t)s3 * C + li * 4];
            acc.x += bf2f(a0.x) + bf2f(a1.x) + bf2f(a2.x) + bf2f(a3.x);
            acc.y += bf2f(a0.y) + bf2f(a1.y) + bf2f(a2.y) + bf2f(a3.y);
            acc.z += bf2f(a0.z) + bf2f(a1.z) + bf2f(a2.z) + bf2f(a3.z);
            acc.w += bf2f(a0.w) + bf2f(a1.w) + bf2f(a2.w) + bf2f(a3.w);
        }
        for (; j < m; j++) {
            int s = __shfl(sv, wl0 + j);
            ushort4 a = *(const ushort4*)&T[(size_t)s * C + li * 4];
            acc.x += bf2f(a.x); acc.y += bf2f(a.y);
            acc.z += bf2f(a.z); acc.w += bf2f(a.w);
        }
    }
    float di = dinv[gw];
    ushort4 tsu = *(const ushort4*)&T[(size_t)gw * C + li * 4];
    float4 bb = *(const float4*)&bias[li * 4];
    float4 o;
    o.x = di * (acc.x + bf2f(tsu.x)) + bb.x;
    o.y = di * (acc.y + bf2f(tsu.y)) + bb.y;
    o.z = di * (acc.z + bf2f(tsu.z)) + bb.z;
    o.w = di * (acc.w + bf2f(tsu.w)) + bb.w;
    if (RELU) {
        o.x = fmaxf(o.x, 0.f); o.y = fmaxf(o.y, 0.f);
        o.z = fmaxf(o.z, 0.f); o.w = fmaxf(o.w, 0.f);
    }
    *(float4*)&H[(size_t)gw * C + li * 4] = o;
}

// ------- final per-edge MLP: y = relu(0.5*(z_s+z_d)+b1) @ w2 + b2 ; Z is bf16 [N,64] -------
__global__ __launch_bounds__(256) void k_edge_mlp(const int* __restrict__ ei, int E,
                                                  const unsigned short* __restrict__ Z,
                                                  const float* __restrict__ b1,
                                                  const float* __restrict__ w2, const float* __restrict__ b2,
                                                  float* __restrict__ out, const int* __restrict__ flag) {
    int is32 = *flag;
    long long t = (long long)blockIdx.x * 256 + threadIdx.x;
    int e = (int)(t >> 4);
    int l = (int)(t & 15);
    if (e >= E) return;
    int s = edge_at(ei, e, is32);
    int d = edge_at(ei, (long long)E + e, is32);
    ushort4 zsu = *(const ushort4*)&Z[(size_t)s * 64 + l * 4];
    ushort4 zdu = *(const ushort4*)&Z[(size_t)d * 64 + l * 4];
    float4 bb = *(const float4*)&b1[l * 4];
    float4 u;
    u.x = fmaxf(0.f, 0.5f * (bf2f(zsu.x) + bf2f(zdu.x)) + bb.x);
    u.y = fmaxf(0.f, 0.5f * (bf2f(zsu.y) + bf2f(zdu.y)) + bb.y);
    u.z = fmaxf(0.f, 0.5f * (bf2f(zsu.z) + bf2f(zdu.z)) + bb.z);
    u.w = fmaxf(0.f, 0.5f * (bf2f(zsu.w) + bf2f(zdu.w)) + bb.w);
    float4 wa = *(const float4*)&w2[l * 8];      // rows l*4, l*4+1 (both cols)
    float4 wb = *(const float4*)&w2[l * 8 + 4];  // rows l*4+2, l*4+3
    float y0 = u.x * wa.x + u.y * wa.z + u.z * wb.x + u.w * wb.z;
    float y1 = u.x * wa.y + u.y * wa.w + u.z * wb.y + u.w * wb.w;
#pragma unroll
    for (int m = 1; m < 16; m <<= 1) {
        y0 += __shfl_xor(y0, m);
        y1 += __shfl_xor(y1, m);
    }
    if (l == 0) out[(size_t)e * 2 + 0] = y0 + b2[0];
    else if (l == 1) out[(size_t)e * 2 + 1] = y1 + b2[1];
}

extern "C" void kernel_launch(void* const* d_in, const int* in_sizes, int n_in,
                              void* d_out, int out_size, void* d_ws, size_t ws_size,
                              hipStream_t stream) {
    const float* x = (const float*)d_in[0];
    const int* ei = (const int*)d_in[1];
    const float* W0 = (const float*)d_in[2];
    const float* b0 = (const float*)d_in[3];
    const float* W1 = (const float*)d_in[4];
    const float* b1 = (const float*)d_in[5];
    const float* W2 = (const float*)d_in[6];
    const float* b2 = (const float*)d_in[7];
    const float* mw1 = (const float*)d_in[8];
    const float* mb1 = (const float*)d_in[9];
    const float* mw2 = (const float*)d_in[10];
    const float* mb2 = (const float*)d_in[11];
    float* out = (float*)d_out;

    int N = in_sizes[0] / 128;
    int E = in_sizes[1] / 2;

    char* p = (char*)d_ws;
    auto alloc = [&](size_t bytes) {
        char* q = p;
        p += (bytes + 255) & ~size_t(255);
        return q;
    };
    float* bufF = (float*)alloc((size_t)N * 128 * 4);            // fp32 aggregate outputs
    unsigned short* bufH = (unsigned short*)alloc((size_t)N * 128 * 2);  // bf16 GEMM outputs
    int* cnt = (int*)alloc((size_t)N * 4);
    int* offs = (int*)alloc((size_t)N * 4);
    float* dinv = (float*)alloc((size_t)N * 4);
    int* csr_src = (int*)alloc((size_t)E * 4);
    int* rank = (int*)alloc((size_t)E * 4);
    int* bsums = (int*)alloc(4096);
    int* flag = (int*)alloc(256);

    hipMemsetAsync(cnt, 0, (size_t)N * 4, stream);
    hipMemsetAsync(flag, 0, 4, stream);

    int gE = (E + 255) / 256;
    int gN = (N + 255) / 256;
    int nchunks = (2 * E) / 4;
    k_detect<<<1024, 256, 0, stream>>>((const int4*)ei, nchunks, flag);
    k_count<<<gE, 256, 0, stream>>>(ei, E, cnt, rank, flag);
    int nb = (N + 1023) / 1024;
    k_scan_local<<<nb, 256, 0, stream>>>(cnt, N, offs, bsums);
    k_scan_bsums<<<1, 1, 0, stream>>>(bsums, nb);
    k_scan_add<<<gN, 256, 0, stream>>>(offs, bsums, cnt, dinv, N);
    k_fill<<<gE, 256, 0, stream>>>(ei, E, offs, rank, csr_src, flag);

    int gG = (N + 63) / 64;
    int gA128 = (N + 7) / 8;    // 8 nodes/block (32-lane groups)
    int gA64 = (N + 15) / 16;   // 16 nodes/block (16-lane groups)

    // layer 0: T' = bf16(dinv ⊙ (x@W0)) ; h0 = relu(dinv ⊙ (agg(T')+T') + b0)
    k_gemm<128, 128, true><<<gG, 256, 0, stream>>>(x, W0, bufH, N, dinv);
    k_aggregate<128, true><<<gA128, 256, 0, stream>>>(bufH, offs, cnt, csr_src, dinv, b0, bufF, N);
    // layer 1
    k_gemm<128, 128, true><<<gG, 256, 0, stream>>>(bufF, W1, bufH, N, dinv);
    k_aggregate<128, true><<<gA128, 256, 0, stream>>>(bufH, offs, cnt, csr_src, dinv, b1, bufF, N);
    // layer 2 (no relu)
    k_gemm<128, 64, true><<<gG, 256, 0, stream>>>(bufF, W2, bufH, N, dinv);
    k_aggregate<64, false><<<gA64, 256, 0, stream>>>(bufH, offs, cnt, csr_src, dinv, b2, bufF, N);
    // z = h2 @ mlp_w1 (linearity: ef@mlp_w1 = 0.5*(z_s+z_d)); bf16 out
    k_gemm<64, 64, false><<<gG, 256, 0, stream>>>(bufF, mw1, bufH, N, nullptr);

    long long totalT = (long long)E * 16;
    int gM = (int)((totalT + 255) / 256);
    k_edge_mlp<<<gM, 256, 0, stream>>>(ei, E, bufH, mb1, mw2, mb2, out, flag);
}